// Round 8
// baseline (290.119 us; speedup 1.0000x reference)
//
#include <hip/hip_runtime.h>

#define B_Q    1024
#define D_K    512
#define N_CLS  200
#define N_KEYS 50000
#define N_PAD  50176            // 196 * 256 VIRTUAL c-rows (no physical pad rows)
#define N_ZT   196              // z-tile index (256-col tiles)
#define NT_TOT 197              // 197 column tiles total
#define KN_ROWS 50200           // physical kn rows: 50000 keys + 200 txt
#define HS     16               // counter stride: 16 ints = 64 B = 1 cacheline

// prep2 row-range bounds (no pad/zero kn rows anymore)
#define PR0 N_KEYS              // keys -> kn rows [0,50000)
#define PR1 (PR0 + B_Q)         // img rows -> qn
#define PR2 (PR1 + N_CLS)       // txt rows -> kn rows [50000,50200)
#define PR3 (PR2 + 400)         // zero d_out rows (400 * 2048B = 819200B)

typedef __attribute__((ext_vector_type(8))) short bf16x8;
typedef __attribute__((ext_vector_type(4))) float f32x4;

__device__ __forceinline__ unsigned short f2bf(float f) {
  union { float f; unsigned int i; } v; v.f = f;
  unsigned int r = v.i + 0x7fffu + ((v.i >> 16) & 1u);
  return (unsigned short)(r >> 16);
}
__device__ __forceinline__ uint4 pack8(const float f[8], float s) {
  uint4 o;
  o.x = (unsigned)f2bf(f[0]*s) | ((unsigned)f2bf(f[1]*s) << 16);
  o.y = (unsigned)f2bf(f[2]*s) | ((unsigned)f2bf(f[3]*s) << 16);
  o.z = (unsigned)f2bf(f[4]*s) | ((unsigned)f2bf(f[5]*s) << 16);
  o.w = (unsigned)f2bf(f[6]*s) | ((unsigned)f2bf(f[7]*s) << 16);
  return o;
}
__device__ __forceinline__ void async_copy16(const void* g, void* lds) {
  __builtin_amdgcn_global_load_lds(
      (const __attribute__((address_space(1))) unsigned int*)g,
      (__attribute__((address_space(3))) unsigned int*)lds, 16, 0, 0);
}

// ---- zero the strided counters: hist[200*HS] + cnt[200*HS] = 6400 ints.
__global__ void k_zero(int* __restrict__ g) {
  int i = blockIdx.x * 1024 + threadIdx.x;
  if (i < 2 * N_CLS * HS) g[i] = 0;
}

// ---- hierarchical parallel rank (R3/R6-verified): per-block (1024 thr) LDS
// ---- histogram of its chunk, ONE cacheline-strided global reservation
// ---- atomic per (block, class), then within-block ranks via LDS atomics.
// ---- Tail [50000,50176): perm -> safe row (N_KEYS), cls -> sentinel; the
// ---- c-epilogue discards sentinel cols, so no physical pad rows needed.
__global__ __launch_bounds__(1024) void k_rank(const int* __restrict__ labels,
                                               const int* __restrict__ ghist,
                                               int* __restrict__ gcnt,
                                               int* __restrict__ perm,
                                               int* __restrict__ cls) {
  __shared__ int incl[N_CLS];
  __shared__ int histl[N_CLS];
  __shared__ int lhist[N_CLS];
  __shared__ int lbase[N_CLS];
  __shared__ int lcur[N_CLS];
  int t = threadIdx.x;
  if (t < N_CLS) {
    int h = ghist[t * HS];
    histl[t] = h; incl[t] = h; lhist[t] = 0;
  }
  __syncthreads();
  for (int d = 1; d < N_CLS; d <<= 1) {          // inclusive scan of ghist
    int x = 0;
    if (t < N_CLS && t >= d) x = incl[t - d];
    __syncthreads();
    if (t < N_CLS) incl[t] += x;
    __syncthreads();
  }
  int n = blockIdx.x * 1024 + t;
  int lab = -1;
  if (n < N_KEYS) {
    lab = labels[n];
    atomicAdd(&lhist[lab], 1);                   // local histogram (LDS)
  }
  __syncthreads();
  if (t < N_CLS && lhist[t] > 0) {               // one reservation per class
    lbase[t] = (incl[t] - histl[t]) + atomicAdd(&gcnt[t * HS], lhist[t]);
    lcur[t] = 0;
  }
  __syncthreads();
  if (n < N_KEYS) {
    int r = atomicAdd(&lcur[lab], 1);            // within-block rank (LDS)
    int d = lbase[lab] + r;
    perm[d] = n;
    cls[d] = lab;
  } else if (n < N_PAD) {
    perm[n] = N_KEYS;                            // safe gather row (discarded)
    cls[n] = N_CLS;                              // sentinel
  }
}

// ---- fused prep: keys(stream-read, normalize, LINEAR write) + histogram +
// ---- img -> qn + txt -> kn rows [50000,50200) + ZERO d_out. No pad rows.
__global__ void k_prep2(const float* __restrict__ keys, const float* __restrict__ img,
                        const float* __restrict__ txt, const int* __restrict__ labels,
                        unsigned short* __restrict__ qn, unsigned short* __restrict__ kn,
                        int* __restrict__ ghist, float* __restrict__ out) {
  int w = threadIdx.x >> 6, lane = threadIdx.x & 63;
  int row = blockIdx.x * 4 + w;
  const float* src; unsigned short* dst;
  if (row < PR0) {
    if (lane == 0) atomicAdd(&ghist[labels[row] * HS], 1);  // strided, no-return
    src = keys + (size_t)row * D_K;
    dst = kn + (size_t)row * D_K;        // original order; k_main gathers via perm
  } else if (row < PR1) {
    int r = row - PR0;
    src = img + (size_t)r * D_K;
    dst = qn + (size_t)r * D_K;
  } else if (row < PR2) {
    int r = row - PR1;
    src = txt + (size_t)r * D_K;
    dst = kn + (size_t)(N_KEYS + r) * D_K;
  } else if (row < PR3) {
    int zr = row - PR2;                   // zero 2 KB of d_out per wave
    uint4* o4 = (uint4*)(out + (size_t)zr * 512) + lane * 2;
    o4[0] = make_uint4(0, 0, 0, 0);
    o4[1] = make_uint4(0, 0, 0, 0);
    return;
  } else return;
  const float4* s4 = (const float4*)src + lane * 2;
  float4 a = s4[0], b = s4[1];
  float f[8] = {a.x, a.y, a.z, a.w, b.x, b.y, b.z, b.w};
  float ss = 0.f;
#pragma unroll
  for (int i = 0; i < 8; i++) ss += f[i] * f[i];
#pragma unroll
  for (int d = 1; d < 64; d <<= 1) ss += __shfl_xor(ss, d);
  float rinv = rsqrtf(ss);
  *((uint4*)dst + lane) = pack8(f, rinv);
}

// ------- main MFMA GEMM: 256x256 tile, 512 thr / 8 waves (2Mx4N), BK=64,
// double-buffered 128 KiB dynamic LDS, 4 phases/K-tile with raw s_barrier
// phase splits + s_setprio around each 16-MFMA quad. Only the K-tile
// boundary __syncthreads drains vmcnt (stages issue in phases 0-1 -> drain
// lands ~3 phases later, covered by MFMA). Within a K-tile, reads touch buf
// p, stage writes touch buf p^1 -> correctness carried by the boundary
// __syncthreads alone. Swizzle/staging algebra byte-identical to the
// verified 128-B-row-stride kernel. Virtual padding: rows >= real data are
// gathered from safe rows and discarded by sentinel/col guards (all rows
// L2-normalized -> |sim|<=1 -> exp bounded). Z-tile reads NO perm/cls
// (fixes R7's OOB reads).
__global__ __launch_bounds__(512, 2) void k_main(const unsigned short* __restrict__ qn,
                                                 const unsigned short* __restrict__ kn,
                                                 const int* __restrict__ cls,
                                                 const int* __restrict__ perm,
                                                 float* __restrict__ out) {
  extern __shared__ unsigned short smem[];   // As[2][16384] | Bs[2][16384] shorts
  int t = threadIdx.x;
  // bijective XCD swizzle for nwg=788 (788%8=4): xcds 0-3 get 99 consecutive
  // work ids, xcds 4-7 get 98 (m204 variant). tileB minor -> each XCD owns
  // contiguous tileN panels (kn panel L2-resident across 4 tileB reuses).
  int bid = blockIdx.x;
  int xcd = bid & 7, bk = bid >> 3;
  int wsw = (xcd < 4 ? xcd * 99 : 396 + (xcd - 4) * 98) + bk;
  int tileN = wsw >> 2, tileB = wsw & 3;
  int rowB0 = tileB * 256, rowN0 = tileN * 256;

  f32x4 acc[8][4];
#pragma unroll
  for (int i = 0; i < 8; i++)
#pragma unroll
    for (int j = 0; j < 4; j++) acc[i][j] = (f32x4){0.f, 0.f, 0.f, 0.f};

  int lane = t & 63, w = t >> 6;
  int wm = (w >> 2) * 128;                     // wave row offset (2 row waves)
  int wcN = (w & 3) * 64;                      // wave col offset (4 col waves)
  int l15 = lane & 15, lq = lane >> 4;
  const int rA = t >> 3;                       // 0..63: row within 64-row chunk
  const int gsw = ((t & 7) ^ (rA & 7)) * 8;    // swizzled source col (shorts)
  const int sw = l15 & 7;                      // un-swizzle key for frag reads

  // gather rows + epilogue class metadata. c-tiles: via perm/cls (all idx
  // < N_PAD, in-bounds). z-tile: direct txt rows, NO perm/cls reads.
  int prow[4];
  int cj[4] = {N_CLS, N_CLS, N_CLS, N_CLS};
  int cseg0 = N_CLS, cseg1 = N_CLS;
  if (tileN < N_ZT) {
#pragma unroll
    for (int c = 0; c < 4; c++) prow[c] = perm[rowN0 + c * 64 + rA];
#pragma unroll
    for (int j = 0; j < 4; j++) cj[j] = cls[rowN0 + wcN + 16 * j + l15];
    cseg0 = cls[rowN0 + wcN];
    cseg1 = cls[rowN0 + wcN + 63];
  } else {
#pragma unroll
    for (int c = 0; c < 4; c++) {
      int r = c * 64 + rA;                     // virtual col row 0..255
      prow[c] = N_KEYS + (r < N_CLS ? r : N_CLS - 1);  // txt rows (clamped)
    }
  }

  auto stageA = [&](int p, int k0) {
    unsigned short* dst = smem + p * 16384;
#pragma unroll
    for (int c = 0; c < 4; c++)
      async_copy16(qn + (size_t)(rowB0 + c * 64 + rA) * D_K + k0 + gsw,
                   dst + c * 4096 + t * 8);
  };
  auto stageB = [&](int p, int k0) {
    unsigned short* dst = smem + 32768 + p * 16384;
#pragma unroll
    for (int c = 0; c < 4; c++)
      async_copy16(kn + (size_t)prow[c] * D_K + k0 + gsw,
                   dst + c * 4096 + t * 8);
  };
  auto quad = [&](int p, int ih, int jh) {     // 12 ds_read_b128 + 16 MFMA
    const unsigned short* A = smem + p * 16384;
    const unsigned short* B = smem + 32768 + p * 16384;
    __builtin_amdgcn_s_setprio(1);
#pragma unroll
    for (int s = 0; s < 2; s++) {
      int cg = ((s * 4 + lq) ^ sw) * 8;
      bf16x8 af[4], bf[2];
#pragma unroll
      for (int i = 0; i < 4; i++) {
        int ra = wm + ih * 64 + 16 * i + l15;
        af[i] = *(const bf16x8*)&A[ra * 64 + cg];
      }
#pragma unroll
      for (int jj = 0; jj < 2; jj++) {
        int rb = wcN + (jh * 2 + jj) * 16 + l15;
        bf[jj] = *(const bf16x8*)&B[rb * 64 + cg];
      }
#pragma unroll
      for (int i = 0; i < 4; i++)
#pragma unroll
        for (int jj = 0; jj < 2; jj++)
          acc[ih * 4 + i][jh * 2 + jj] = __builtin_amdgcn_mfma_f32_16x16x32_bf16(
              af[i], bf[jj], acc[ih * 4 + i][jh * 2 + jj], 0, 0, 0);
    }
    __builtin_amdgcn_s_setprio(0);
  };

  stageA(0, 0); stageB(0, 0);
  __syncthreads();                             // prologue drain: buf0 ready
  for (int kt = 0; kt < 8; ++kt) {
    int p = kt & 1, k0n = (kt + 1) * 64;
    if (kt < 7) stageA(p ^ 1, k0n);            // phase 0: stage A(next) | MFMA
    quad(p, 0, 0);
    __builtin_amdgcn_s_barrier();              // raw: no vmcnt drain
    if (kt < 7) stageB(p ^ 1, k0n);            // phase 1: stage B(next) | MFMA
    quad(p, 0, 1);
    __builtin_amdgcn_s_barrier();
    quad(p, 1, 0);                             // phase 2
    __builtin_amdgcn_s_barrier();
    quad(p, 1, 1);                             // phase 3
    __syncthreads();                           // boundary: drains vmcnt(0) ->
  }                                            // buf p^1 staged+visible

  if (tileN >= N_ZT) {
    // z-tile: out[row][col] += 0.5 * 100 * sim  (out pre-zeroed by k_prep2)
#pragma unroll
    for (int i = 0; i < 8; i++)
#pragma unroll
      for (int j = 0; j < 4; j++) {
        int col = wcN + 16 * j + l15;          // rowN0 == N_PAD here
        if (col < N_CLS) {
#pragma unroll
          for (int r = 0; r < 4; r++) {
            int row = rowB0 + wm + 16 * i + lq * 4 + r;
            atomicAdd(out + (size_t)row * N_CLS + col, 50.0f * acc[i][j][r]);
          }
        }
      }
    return;
  }

  // c-tile: aff = exp(5*sim); segment-sum over sorted classes; atomicAdd 0.5*sum
#pragma unroll
  for (int i = 0; i < 8; i++)
#pragma unroll
    for (int j = 0; j < 4; j++)
#pragma unroll
      for (int r = 0; r < 4; r++) acc[i][j][r] = __expf(5.0f * acc[i][j][r]);

  for (int c = cseg0; c <= cseg1; c++) {
    if (c >= N_CLS) break;  // pad sentinel; all later cols are pad too
#pragma unroll
    for (int i = 0; i < 8; i++) {
      float s0 = 0.f, s1 = 0.f, s2 = 0.f, s3 = 0.f;
#pragma unroll
      for (int j = 0; j < 4; j++) {
        if (cj[j] == c) {
          s0 += acc[i][j][0]; s1 += acc[i][j][1];
          s2 += acc[i][j][2]; s3 += acc[i][j][3];
        }
      }
#pragma unroll
      for (int d = 1; d < 16; d <<= 1) {
        s0 += __shfl_xor(s0, d); s1 += __shfl_xor(s1, d);
        s2 += __shfl_xor(s2, d); s3 += __shfl_xor(s3, d);
      }
      if (l15 == 0) {
        int row = rowB0 + wm + 16 * i + lq * 4;
        float* o = out + (size_t)row * N_CLS + c;
        if (s0 != 0.f) atomicAdd(o + 0 * N_CLS, 0.5f * s0);
        if (s1 != 0.f) atomicAdd(o + 1 * N_CLS, 0.5f * s1);
        if (s2 != 0.f) atomicAdd(o + 2 * N_CLS, 0.5f * s2);
        if (s3 != 0.f) atomicAdd(o + 3 * N_CLS, 0.5f * s3);
      }
    }
  }
}

extern "C" void kernel_launch(void* const* d_in, const int* in_sizes, int n_in,
                              void* d_out, int out_size, void* d_ws, size_t ws_size,
                              hipStream_t stream) {
  (void)in_sizes; (void)n_in; (void)out_size; (void)ws_size;
  const float* img    = (const float*)d_in[0];
  const float* txt    = (const float*)d_in[1];
  const float* keys   = (const float*)d_in[2];
  const int*   labels = (const int*)d_in[3];
  float*       out    = (float*)d_out;

  char* ws = (char*)d_ws;
  // workspace layout (bytes) — total 52,880,384 < R0-verified 52,961,280
  unsigned short* qn = (unsigned short*)(ws + 0);         // 1024*512*2   = 1,048,576
  unsigned short* kn = (unsigned short*)(ws + 1048576);   // 50200*512*2  = 51,404,800
  int*  perm = (int*)(ws + 52453376);                     // 50176*4 = 200,704
  int*  cls  = (int*)(ws + 52654080);                     // 50176*4 = 200,704
  int*  gz   = (int*)(ws + 52854784);                     // 6400*4  =  25,600

  // allow 128 KiB dynamic LDS for k_main (immediate API, graph-capture safe)
  hipFuncSetAttribute((const void*)k_main,
                      hipFuncAttributeMaxDynamicSharedMemorySize, 131072);

  // 4 graph nodes: zero + prep2 + rank + main
  k_zero<<<7, 1024, 0, stream>>>(gz);
  k_prep2<<<(PR3 + 3) / 4, 256, 0, stream>>>(keys, img, txt, labels, qn, kn, gz, out);
  k_rank<<<N_PAD / 1024, 1024, 0, stream>>>(labels, gz, gz + N_CLS * HS, perm, cls);
  k_main<<<dim3(4 * NT_TOT), 512, 131072, stream>>>(qn, kn, cls, perm, out);
}

// Round 9
// 274.122 us; speedup vs baseline: 1.0584x; 1.0584x over previous
//
#include <hip/hip_runtime.h>

#define B_Q    1024
#define D_K    512
#define N_CLS  200
#define N_KEYS 50000
#define N_PAD  50176            // 196 * 256 VIRTUAL c-rows (no physical pad rows)
#define N_ZT   196              // z-tile index (256-col tiles)
#define NT_TOT 197              // 197 column tiles total
#define KN_ROWS 50200           // physical kn rows: 50000 keys + 200 txt
#define HS     16               // counter stride: 16 ints = 64 B = 1 cacheline

// prep2 row-range bounds (no pad/zero kn rows)
#define PR0 N_KEYS              // keys -> kn rows [0,50000)
#define PR1 (PR0 + B_Q)         // img rows -> qn
#define PR2 (PR1 + N_CLS)       // txt rows -> kn rows [50000,50200)
#define PR3 (PR2 + 400)         // zero d_out rows (400 * 2048B = 819200B)

typedef __attribute__((ext_vector_type(8))) short bf16x8;
typedef __attribute__((ext_vector_type(4))) float f32x4;

__device__ __forceinline__ unsigned short f2bf(float f) {
  union { float f; unsigned int i; } v; v.f = f;
  unsigned int r = v.i + 0x7fffu + ((v.i >> 16) & 1u);
  return (unsigned short)(r >> 16);
}
__device__ __forceinline__ uint4 pack8(const float f[8], float s) {
  uint4 o;
  o.x = (unsigned)f2bf(f[0]*s) | ((unsigned)f2bf(f[1]*s) << 16);
  o.y = (unsigned)f2bf(f[2]*s) | ((unsigned)f2bf(f[3]*s) << 16);
  o.z = (unsigned)f2bf(f[4]*s) | ((unsigned)f2bf(f[5]*s) << 16);
  o.w = (unsigned)f2bf(f[6]*s) | ((unsigned)f2bf(f[7]*s) << 16);
  return o;
}
__device__ __forceinline__ void async_copy16(const void* g, void* lds) {
  __builtin_amdgcn_global_load_lds(
      (const __attribute__((address_space(1))) unsigned int*)g,
      (__attribute__((address_space(3))) unsigned int*)lds, 16, 0, 0);
}

// ---- zero the strided counters: hist[200*HS] + cnt[200*HS] = 6400 ints.
__global__ void k_zero(int* __restrict__ g) {
  int i = blockIdx.x * 1024 + threadIdx.x;
  if (i < 2 * N_CLS * HS) g[i] = 0;
}

// ---- hierarchical parallel rank (R3/R6/R8-verified): per-block (1024 thr)
// ---- LDS histogram of its chunk, ONE cacheline-strided global reservation
// ---- atomic per (block, class), then within-block ranks via LDS atomics.
// ---- Tail [50000,50176): perm -> safe row, cls -> sentinel (virtual pad).
__global__ __launch_bounds__(1024) void k_rank(const int* __restrict__ labels,
                                               const int* __restrict__ ghist,
                                               int* __restrict__ gcnt,
                                               int* __restrict__ perm,
                                               int* __restrict__ cls) {
  __shared__ int incl[N_CLS];
  __shared__ int histl[N_CLS];
  __shared__ int lhist[N_CLS];
  __shared__ int lbase[N_CLS];
  __shared__ int lcur[N_CLS];
  int t = threadIdx.x;
  if (t < N_CLS) {
    int h = ghist[t * HS];
    histl[t] = h; incl[t] = h; lhist[t] = 0;
  }
  __syncthreads();
  for (int d = 1; d < N_CLS; d <<= 1) {          // inclusive scan of ghist
    int x = 0;
    if (t < N_CLS && t >= d) x = incl[t - d];
    __syncthreads();
    if (t < N_CLS) incl[t] += x;
    __syncthreads();
  }
  int n = blockIdx.x * 1024 + t;
  int lab = -1;
  if (n < N_KEYS) {
    lab = labels[n];
    atomicAdd(&lhist[lab], 1);                   // local histogram (LDS)
  }
  __syncthreads();
  if (t < N_CLS && lhist[t] > 0) {               // one reservation per class
    lbase[t] = (incl[t] - histl[t]) + atomicAdd(&gcnt[t * HS], lhist[t]);
    lcur[t] = 0;
  }
  __syncthreads();
  if (n < N_KEYS) {
    int r = atomicAdd(&lcur[lab], 1);            // within-block rank (LDS)
    int d = lbase[lab] + r;
    perm[d] = n;
    cls[d] = lab;
  } else if (n < N_PAD) {
    perm[n] = N_KEYS;                            // safe gather row (discarded)
    cls[n] = N_CLS;                              // sentinel
  }
}

// ---- fused prep: keys(stream-read, normalize, LINEAR write) + histogram +
// ---- img -> qn + txt -> kn rows [50000,50200) + ZERO d_out.
__global__ void k_prep2(const float* __restrict__ keys, const float* __restrict__ img,
                        const float* __restrict__ txt, const int* __restrict__ labels,
                        unsigned short* __restrict__ qn, unsigned short* __restrict__ kn,
                        int* __restrict__ ghist, float* __restrict__ out) {
  int w = threadIdx.x >> 6, lane = threadIdx.x & 63;
  int row = blockIdx.x * 4 + w;
  const float* src; unsigned short* dst;
  if (row < PR0) {
    if (lane == 0) atomicAdd(&ghist[labels[row] * HS], 1);  // strided, no-return
    src = keys + (size_t)row * D_K;
    dst = kn + (size_t)row * D_K;        // original order; k_main gathers via perm
  } else if (row < PR1) {
    int r = row - PR0;
    src = img + (size_t)r * D_K;
    dst = qn + (size_t)r * D_K;
  } else if (row < PR2) {
    int r = row - PR1;
    src = txt + (size_t)r * D_K;
    dst = kn + (size_t)(N_KEYS + r) * D_K;
  } else if (row < PR3) {
    int zr = row - PR2;                   // zero 2 KB of d_out per wave
    uint4* o4 = (uint4*)(out + (size_t)zr * 512) + lane * 2;
    o4[0] = make_uint4(0, 0, 0, 0);
    o4[1] = make_uint4(0, 0, 0, 0);
    return;
  } else return;
  const float4* s4 = (const float4*)src + lane * 2;
  float4 a = s4[0], b = s4[1];
  float f[8] = {a.x, a.y, a.z, a.w, b.x, b.y, b.z, b.w};
  float ss = 0.f;
#pragma unroll
  for (int i = 0; i < 8; i++) ss += f[i] * f[i];
#pragma unroll
  for (int d = 1; d < 64; d <<= 1) ss += __shfl_xor(ss, d);
  float rinv = rsqrtf(ss);
  *((uint4*)dst + lane) = pack8(f, rinv);
}

// ------- main MFMA GEMM: 128(M)x256(N) tile, 512 thr / 8 waves (2Mx4N),
// per-wave 64x64 out -> acc[4][4] = 64 regs (R8's 128-reg acc hit the
// 256/wave unified cap and SPILLED: WRITE_SIZE 76 MB, VGPR pinned at 128).
// Phase schedule identical to R8 (correctness-verified there): 4 phases/
// K-tile {8 MFMA each} split by raw s_barrier, stageA in ph0, stageB in ph1,
// vmcnt drain only at the K-tile boundary __syncthreads. LDS 96 KB dbuf
// (1 block/CU). Swizzle/staging algebra byte-identical to the verified
// 128-B-row-stride layout. Virtual padding via perm/cls sentinels.
__global__ __launch_bounds__(512, 2) void k_main(const unsigned short* __restrict__ qn,
                                                 const unsigned short* __restrict__ kn,
                                                 const int* __restrict__ cls,
                                                 const int* __restrict__ perm,
                                                 float* __restrict__ out) {
  extern __shared__ unsigned short smem[];   // As[2][8192] | Bs[2][16384] shorts
  int t = threadIdx.x;
  // bijective XCD swizzle: nwg = 8*197 = 1576, nwg%8==0 -> xcd = bid&7 owns
  // 197 consecutive work ids (tileB minor -> kn panel L2-resident across 8
  // tileB reuses).
  int bid = blockIdx.x;
  int wsw = (bid & 7) * NT_TOT + (bid >> 3);
  int tileN = wsw >> 3, tileB = wsw & 7;
  int rowB0 = tileB * 128, rowN0 = tileN * 256;

  f32x4 acc[4][4];
#pragma unroll
  for (int i = 0; i < 4; i++)
#pragma unroll
    for (int j = 0; j < 4; j++) acc[i][j] = (f32x4){0.f, 0.f, 0.f, 0.f};

  int lane = t & 63, w = t >> 6;
  int wr = (w >> 2) * 64;                      // wave row offset (2 M-waves)
  int wc = (w & 3) * 64;                       // wave col offset (4 N-waves)
  int l15 = lane & 15, lq = lane >> 4;
  const int rA = t >> 3;                       // 0..63: row within 64-row chunk
  const int gsw = ((t & 7) ^ (rA & 7)) * 8;    // swizzled source col (shorts)
  const int sw = l15 & 7;                      // un-swizzle key for frag reads

  // gather rows + epilogue class metadata. c-tiles via perm/cls (idx < N_PAD,
  // in-bounds); z-tile: direct txt rows, NO perm/cls reads.
  int prow[4];
  int cj[4] = {N_CLS, N_CLS, N_CLS, N_CLS};
  int cseg0 = N_CLS, cseg1 = N_CLS;
  if (tileN < N_ZT) {
#pragma unroll
    for (int c = 0; c < 4; c++) prow[c] = perm[rowN0 + c * 64 + rA];
#pragma unroll
    for (int j = 0; j < 4; j++) cj[j] = cls[rowN0 + wc + 16 * j + l15];
    cseg0 = cls[rowN0 + wc];
    cseg1 = cls[rowN0 + wc + 63];
  } else {
#pragma unroll
    for (int c = 0; c < 4; c++) {
      int r = c * 64 + rA;                     // virtual col row 0..255
      prow[c] = N_KEYS + (r < N_CLS ? r : N_CLS - 1);  // txt rows (clamped)
    }
  }

  auto stageA = [&](int p, int k0) {           // 128x64 tile: 2 rounds
    unsigned short* dst = smem + p * 8192;
#pragma unroll
    for (int c = 0; c < 2; c++)
      async_copy16(qn + (size_t)(rowB0 + c * 64 + rA) * D_K + k0 + gsw,
                   dst + c * 4096 + t * 8);
  };
  auto stageB = [&](int p, int k0) {           // 256x64 tile: 4 rounds
    unsigned short* dst = smem + 16384 + p * 16384;
#pragma unroll
    for (int c = 0; c < 4; c++)
      async_copy16(kn + (size_t)prow[c] * D_K + k0 + gsw,
                   dst + c * 4096 + t * 8);
  };

  bf16x8 af[4];
  auto ldA = [&](int p, int s) {               // A frags for K-half s
    const unsigned short* A = smem + p * 8192;
    int cg = ((s * 4 + lq) ^ sw) * 8;
#pragma unroll
    for (int i = 0; i < 4; i++) {
      int ra = wr + 16 * i + l15;
      af[i] = *(const bf16x8*)&A[ra * 64 + cg];
    }
  };
  auto mfma8 = [&](int p, int s, int jh) {     // 2 ds_read + 8 MFMA
    const unsigned short* B = smem + 16384 + p * 16384;
    int cg = ((s * 4 + lq) ^ sw) * 8;
    bf16x8 bf[2];
#pragma unroll
    for (int jj = 0; jj < 2; jj++) {
      int rb = wc + (jh * 2 + jj) * 16 + l15;
      bf[jj] = *(const bf16x8*)&B[rb * 64 + cg];
    }
    __builtin_amdgcn_s_setprio(1);
#pragma unroll
    for (int i = 0; i < 4; i++)
#pragma unroll
      for (int jj = 0; jj < 2; jj++)
        acc[i][jh * 2 + jj] = __builtin_amdgcn_mfma_f32_16x16x32_bf16(
            af[i], bf[jj], acc[i][jh * 2 + jj], 0, 0, 0);
    __builtin_amdgcn_s_setprio(0);
  };

  stageA(0, 0); stageB(0, 0);
  __syncthreads();                             // prologue drain: buf0 ready
  for (int kt = 0; kt < 8; ++kt) {
    int p = kt & 1, k0n = (kt + 1) * 64;
    if (kt < 7) stageA(p ^ 1, k0n);            // ph0: stage A(next) | 8 MFMA
    ldA(p, 0);
    mfma8(p, 0, 0);
    __builtin_amdgcn_s_barrier();              // raw: no vmcnt drain
    if (kt < 7) stageB(p ^ 1, k0n);            // ph1: stage B(next) | 8 MFMA
    mfma8(p, 0, 1);
    __builtin_amdgcn_s_barrier();
    ldA(p, 1);                                 // ph2
    mfma8(p, 1, 0);
    __builtin_amdgcn_s_barrier();
    mfma8(p, 1, 1);                            // ph3
    __syncthreads();                           // boundary: drains vmcnt(0)
  }

  if (tileN >= N_ZT) {
    // z-tile: out[row][col] += 0.5 * 100 * sim  (out pre-zeroed by k_prep2)
#pragma unroll
    for (int i = 0; i < 4; i++)
#pragma unroll
      for (int j = 0; j < 4; j++) {
        int col = wc + 16 * j + l15;           // rowN0 == N_PAD here
        if (col < N_CLS) {
#pragma unroll
          for (int r = 0; r < 4; r++) {
            int row = rowB0 + wr + 16 * i + lq * 4 + r;
            atomicAdd(out + (size_t)row * N_CLS + col, 50.0f * acc[i][j][r]);
          }
        }
      }
    return;
  }

  // c-tile: aff = exp(5*sim); segment-sum over sorted classes; atomicAdd 0.5*sum
#pragma unroll
  for (int i = 0; i < 4; i++)
#pragma unroll
    for (int j = 0; j < 4; j++)
#pragma unroll
      for (int r = 0; r < 4; r++) acc[i][j][r] = __expf(5.0f * acc[i][j][r]);

  for (int c = cseg0; c <= cseg1; c++) {
    if (c >= N_CLS) break;  // pad sentinel; all later cols are pad too
#pragma unroll
    for (int i = 0; i < 4; i++) {
      float s0 = 0.f, s1 = 0.f, s2 = 0.f, s3 = 0.f;
#pragma unroll
      for (int j = 0; j < 4; j++) {
        if (cj[j] == c) {
          s0 += acc[i][j][0]; s1 += acc[i][j][1];
          s2 += acc[i][j][2]; s3 += acc[i][j][3];
        }
      }
#pragma unroll
      for (int d = 1; d < 16; d <<= 1) {
        s0 += __shfl_xor(s0, d); s1 += __shfl_xor(s1, d);
        s2 += __shfl_xor(s2, d); s3 += __shfl_xor(s3, d);
      }
      if (l15 == 0) {
        int row = rowB0 + wr + 16 * i + lq * 4;
        float* o = out + (size_t)row * N_CLS + c;
        if (s0 != 0.f) atomicAdd(o + 0 * N_CLS, 0.5f * s0);
        if (s1 != 0.f) atomicAdd(o + 1 * N_CLS, 0.5f * s1);
        if (s2 != 0.f) atomicAdd(o + 2 * N_CLS, 0.5f * s2);
        if (s3 != 0.f) atomicAdd(o + 3 * N_CLS, 0.5f * s3);
      }
    }
  }
}

extern "C" void kernel_launch(void* const* d_in, const int* in_sizes, int n_in,
                              void* d_out, int out_size, void* d_ws, size_t ws_size,
                              hipStream_t stream) {
  (void)in_sizes; (void)n_in; (void)out_size; (void)ws_size;
  const float* img    = (const float*)d_in[0];
  const float* txt    = (const float*)d_in[1];
  const float* keys   = (const float*)d_in[2];
  const int*   labels = (const int*)d_in[3];
  float*       out    = (float*)d_out;

  char* ws = (char*)d_ws;
  // workspace layout (bytes) — total 52,880,384 (R8-verified fits)
  unsigned short* qn = (unsigned short*)(ws + 0);         // 1024*512*2   = 1,048,576
  unsigned short* kn = (unsigned short*)(ws + 1048576);   // 50200*512*2  = 51,404,800
  int*  perm = (int*)(ws + 52453376);                     // 50176*4 = 200,704
  int*  cls  = (int*)(ws + 52654080);                     // 50176*4 = 200,704
  int*  gz   = (int*)(ws + 52854784);                     // 6400*4  =  25,600

  // allow 96 KiB dynamic LDS for k_main (immediate API, graph-capture safe)
  hipFuncSetAttribute((const void*)k_main,
                      hipFuncAttributeMaxDynamicSharedMemorySize, 98304);

  // 4 graph nodes: zero + prep2 + rank + main
  k_zero<<<7, 1024, 0, stream>>>(gz);
  k_prep2<<<(PR3 + 3) / 4, 256, 0, stream>>>(keys, img, txt, labels, qn, kn, gz, out);
  k_rank<<<N_PAD / 1024, 1024, 0, stream>>>(labels, gz, gz + N_CLS * HS, perm, cls);
  k_main<<<dim3(8 * NT_TOT), 512, 98304, stream>>>(qn, kn, cls, perm, out);
}

// Round 10
// 255.343 us; speedup vs baseline: 1.1362x; 1.0735x over previous
//
#include <hip/hip_runtime.h>

#define B_Q    1024
#define D_K    512
#define N_CLS  200
#define N_KEYS 50000
#define N_PAD  50048            // 391 * 128 (keys + pad rows)
#define N_ZT   (N_PAD / 128)    // 391: first z-tile index
#define NT_TOT (N_ZT + 2)       // 393 column tiles total
#define KN_ROWS 50304           // N_PAD + 256 (txt + zero tail)
#define HS     16               // counter stride: 16 ints = 64 B = 1 cacheline

// prep2 row-range bounds
#define R0 N_PAD                // keys + pad rows -> kn (original order)
#define R1 (R0 + B_Q)           // img rows -> qn
#define R2 (R1 + N_CLS)         // txt rows -> kn tail
#define R3 (R2 + 56)            // zero kn tail rows
#define R4 (R3 + 400)           // zero d_out rows (400 * 2048B = 819200B)

typedef __attribute__((ext_vector_type(8))) short bf16x8;
typedef __attribute__((ext_vector_type(4))) float f32x4;

__device__ __forceinline__ unsigned short f2bf(float f) {
  union { float f; unsigned int i; } v; v.f = f;
  unsigned int r = v.i + 0x7fffu + ((v.i >> 16) & 1u);
  return (unsigned short)(r >> 16);
}
__device__ __forceinline__ uint4 pack8(const float f[8], float s) {
  uint4 o;
  o.x = (unsigned)f2bf(f[0]*s) | ((unsigned)f2bf(f[1]*s) << 16);
  o.y = (unsigned)f2bf(f[2]*s) | ((unsigned)f2bf(f[3]*s) << 16);
  o.z = (unsigned)f2bf(f[4]*s) | ((unsigned)f2bf(f[5]*s) << 16);
  o.w = (unsigned)f2bf(f[6]*s) | ((unsigned)f2bf(f[7]*s) << 16);
  return o;
}
__device__ __forceinline__ void async_copy16(const void* g, void* lds) {
  __builtin_amdgcn_global_load_lds(
      (const __attribute__((address_space(1))) unsigned int*)g,
      (__attribute__((address_space(3))) unsigned int*)lds, 16, 0, 0);
}

// ---- zero the strided counters: hist[200*HS] + cnt[200*HS] = 6400 ints.
__global__ void k_zero(int* __restrict__ g) {
  int i = blockIdx.x * 1024 + threadIdx.x;
  if (i < 2 * N_CLS * HS) g[i] = 0;
}

// ---- hierarchical parallel rank (R3/R6-verified): per-block (1024 thr) LDS
// ---- histogram of its chunk, ONE cacheline-strided global reservation
// ---- atomic per (block, class) (~9.6k total), then within-block ranks via
// ---- LDS atomics. Any within-class order is valid.
__global__ __launch_bounds__(1024) void k_rank(const int* __restrict__ labels,
                                               const int* __restrict__ ghist,
                                               int* __restrict__ gcnt,
                                               int* __restrict__ perm,
                                               int* __restrict__ cls) {
  __shared__ int incl[N_CLS];
  __shared__ int histl[N_CLS];
  __shared__ int lhist[N_CLS];
  __shared__ int lbase[N_CLS];
  __shared__ int lcur[N_CLS];
  int t = threadIdx.x;
  if (t < N_CLS) {
    int h = ghist[t * HS];
    histl[t] = h; incl[t] = h; lhist[t] = 0;
  }
  __syncthreads();
  for (int d = 1; d < N_CLS; d <<= 1) {          // inclusive scan of ghist
    int x = 0;
    if (t < N_CLS && t >= d) x = incl[t - d];
    __syncthreads();
    if (t < N_CLS) incl[t] += x;
    __syncthreads();
  }
  int n = blockIdx.x * 1024 + t;
  int lab = -1;
  if (n < N_KEYS) {
    lab = labels[n];
    atomicAdd(&lhist[lab], 1);                   // local histogram (LDS)
  }
  __syncthreads();
  if (t < N_CLS && lhist[t] > 0) {               // one reservation per class
    lbase[t] = (incl[t] - histl[t]) + atomicAdd(&gcnt[t * HS], lhist[t]);
    lcur[t] = 0;
  }
  __syncthreads();
  if (n < N_KEYS) {
    int r = atomicAdd(&lcur[lab], 1);            // within-block rank (LDS)
    int d = lbase[lab] + r;
    perm[d] = n;
    cls[d] = lab;
  } else if (n < KN_ROWS) {
    perm[n] = n;                                 // pad / txt / zero-tail
    cls[n] = N_CLS;                              // sentinel
  }
}

// ---- fused prep: keys(stream-read, normalize, LINEAR write) + histogram +
// ---- img -> qn + txt -> kn tail + zero pads + ZERO d_out. No sort dep.
__global__ void k_prep2(const float* __restrict__ keys, const float* __restrict__ img,
                        const float* __restrict__ txt, const int* __restrict__ labels,
                        unsigned short* __restrict__ qn, unsigned short* __restrict__ kn,
                        int* __restrict__ ghist, float* __restrict__ out) {
  int w = threadIdx.x >> 6, lane = threadIdx.x & 63;
  int row = blockIdx.x * 4 + w;
  const float* src; unsigned short* dst;
  if (row < R0) {
    if (row >= N_KEYS) {  // pad row: zero
      *((uint4*)(kn + (size_t)row * D_K) + lane) = make_uint4(0, 0, 0, 0);
      return;
    }
    if (lane == 0) atomicAdd(&ghist[labels[row] * HS], 1);  // strided, no-return
    src = keys + (size_t)row * D_K;
    dst = kn + (size_t)row * D_K;        // original order; k_main gathers via perm
  } else if (row < R1) {
    int r = row - R0;
    src = img + (size_t)r * D_K;
    dst = qn + (size_t)r * D_K;
  } else if (row < R2) {
    int r = row - R1;
    src = txt + (size_t)r * D_K;
    dst = kn + (size_t)(N_PAD + r) * D_K;
  } else if (row < R3) {
    int r = N_PAD + N_CLS + (row - R2);   // zero tail kn rows
    *((uint4*)(kn + (size_t)r * D_K) + lane) = make_uint4(0, 0, 0, 0);
    return;
  } else if (row < R4) {
    int zr = row - R3;                    // zero 2 KB of d_out per wave
    uint4* o4 = (uint4*)(out + (size_t)zr * 512) + lane * 2;
    o4[0] = make_uint4(0, 0, 0, 0);
    o4[1] = make_uint4(0, 0, 0, 0);
    return;
  } else return;
  const float4* s4 = (const float4*)src + lane * 2;
  float4 a = s4[0], b = s4[1];
  float f[8] = {a.x, a.y, a.z, a.w, b.x, b.y, b.z, b.w};
  float ss = 0.f;
#pragma unroll
  for (int i = 0; i < 8; i++) ss += f[i] * f[i];
#pragma unroll
  for (int d = 1; d < 64; d <<= 1) ss += __shfl_xor(ss, d);
  float rinv = rsqrtf(ss);
  *((uint4*)dst + lane) = pack8(f, rinv);
}

// ------- main MFMA GEMM: verified 89.4 µs structure (R2/R4/R6) — single
// 32 KB LDS buffer, two barriers per K-step, (256,3)/80-VGPR, 0 conflicts.
// FINAL after 5 restructure attempts regressed: R3 64KB-dbuf (occupancy
// 2.7->1.5 lost cross-block overlap), R5 BK=32 (6.4M bank conflicts),
// R8 256^2 8-phase (acc spill at 256-reg cap), R9 128x256 8-phase (clean
// counters, still 110 µs: K=512 = 8 K-tiles is too shallow to amortize a
// 1-block/CU pipeline; cross-block overlap at 27% occupancy wins here).
// Kept: XCD panel swizzle (FETCH 203->30 MB), perm-gather, XOR swizzle.
__global__ __launch_bounds__(256, 3) void k_main(const unsigned short* __restrict__ qn,
                                                 const unsigned short* __restrict__ kn,
                                                 const int* __restrict__ cls,
                                                 const int* __restrict__ perm,
                                                 float* __restrict__ out) {
  __shared__ unsigned short As[128 * 64];
  __shared__ unsigned short Bs[128 * 64];
  int t = threadIdx.x;
  // bijective XCD swizzle: xcd = id%8 gets work ids [xcd*393, (xcd+1)*393)
  int wsw = (blockIdx.x & 7) * NT_TOT + (blockIdx.x >> 3);
  int tileN = wsw >> 3, tileB = wsw & 7;
  int rowB0 = tileB * 128, rowN0 = tileN * 128;

  f32x4 acc[4][4];
#pragma unroll
  for (int i = 0; i < 4; i++)
#pragma unroll
    for (int j = 0; j < 4; j++) acc[i][j] = (f32x4){0.f, 0.f, 0.f, 0.f};

  int lane = t & 63, w = t >> 6;
  int wr = (w >> 1) * 64, wc = (w & 1) * 64;
  int l15 = lane & 15, lq = lane >> 4;
  const int rA = t >> 3;                       // 0..31: row within 32-row chunk
  const int gsw = ((t & 7) ^ (rA & 7)) * 8;    // swizzled source col (shorts)
  const int sw = l15 & 7;                      // un-swizzle key for frag reads

  // prefetch gather rows + epilogue class metadata (hidden under K-loop)
  int prow[4];
#pragma unroll
  for (int i = 0; i < 4; i++) prow[i] = perm[rowN0 + i * 32 + rA];
  int cj[4];
#pragma unroll
  for (int j = 0; j < 4; j++) cj[j] = cls[rowN0 + wc + 16 * j + l15];
  int cseg0 = cls[rowN0 + wc];
  int cseg1 = cls[rowN0 + wc + 63];

  for (int k0 = 0; k0 < D_K; k0 += 64) {
    __syncthreads();
#pragma unroll
    for (int i = 0; i < 4; i++) {
      int row = i * 32 + rA;
      async_copy16(qn + (size_t)(rowB0 + row) * D_K + k0 + gsw, &As[i * 2048 + t * 8]);
      async_copy16(kn + (size_t)prow[i] * D_K + k0 + gsw, &Bs[i * 2048 + t * 8]);
    }
    __syncthreads();
#pragma unroll
    for (int ks = 0; ks < 64; ks += 32) {
      bf16x8 af[4], bf[4];
#pragma unroll
      for (int i = 0; i < 4; i++)
        af[i] = *(const bf16x8*)&As[(wr + 16 * i + l15) * 64 + ((((ks >> 3) + lq) ^ sw) * 8)];
#pragma unroll
      for (int j = 0; j < 4; j++)
        bf[j] = *(const bf16x8*)&Bs[(wc + 16 * j + l15) * 64 + ((((ks >> 3) + lq) ^ sw) * 8)];
#pragma unroll
      for (int i = 0; i < 4; i++)
#pragma unroll
        for (int j = 0; j < 4; j++)
          acc[i][j] = __builtin_amdgcn_mfma_f32_16x16x32_bf16(af[i], bf[j], acc[i][j], 0, 0, 0);
    }
  }

  if (tileN >= N_ZT) {
    // z-tile: out[row][col] += 0.5 * 100 * sim  (out pre-zeroed by k_prep2)
#pragma unroll
    for (int i = 0; i < 4; i++)
#pragma unroll
      for (int j = 0; j < 4; j++) {
        int col = rowN0 + wc + 16 * j + l15 - N_PAD;
        if (col < N_CLS) {
#pragma unroll
          for (int r = 0; r < 4; r++) {
            int row = rowB0 + wr + 16 * i + lq * 4 + r;
            atomicAdd(out + (size_t)row * N_CLS + col, 50.0f * acc[i][j][r]);
          }
        }
      }
    return;
  }

  // c-tile: aff = exp(5*sim); segment-sum over sorted classes; atomicAdd 0.5*sum
#pragma unroll
  for (int i = 0; i < 4; i++)
#pragma unroll
    for (int j = 0; j < 4; j++)
#pragma unroll
      for (int r = 0; r < 4; r++) acc[i][j][r] = __expf(5.0f * acc[i][j][r]);

  for (int c = cseg0; c <= cseg1; c++) {
    if (c >= N_CLS) break;  // pad sentinel; all later cols are pad too
#pragma unroll
    for (int i = 0; i < 4; i++) {
      float s0 = 0.f, s1 = 0.f, s2 = 0.f, s3 = 0.f;
#pragma unroll
      for (int j = 0; j < 4; j++) {
        if (cj[j] == c) {
          s0 += acc[i][j][0]; s1 += acc[i][j][1];
          s2 += acc[i][j][2]; s3 += acc[i][j][3];
        }
      }
#pragma unroll
      for (int d = 1; d < 16; d <<= 1) {
        s0 += __shfl_xor(s0, d); s1 += __shfl_xor(s1, d);
        s2 += __shfl_xor(s2, d); s3 += __shfl_xor(s3, d);
      }
      if (l15 == 0) {
        int row = rowB0 + wr + 16 * i + lq * 4;
        float* o = out + (size_t)row * N_CLS + c;
        if (s0 != 0.f) atomicAdd(o + 0 * N_CLS, 0.5f * s0);
        if (s1 != 0.f) atomicAdd(o + 1 * N_CLS, 0.5f * s1);
        if (s2 != 0.f) atomicAdd(o + 2 * N_CLS, 0.5f * s2);
        if (s3 != 0.f) atomicAdd(o + 3 * N_CLS, 0.5f * s3);
      }
    }
  }
}

extern "C" void kernel_launch(void* const* d_in, const int* in_sizes, int n_in,
                              void* d_out, int out_size, void* d_ws, size_t ws_size,
                              hipStream_t stream) {
  (void)in_sizes; (void)n_in; (void)out_size; (void)ws_size;
  const float* img    = (const float*)d_in[0];
  const float* txt    = (const float*)d_in[1];
  const float* keys   = (const float*)d_in[2];
  const int*   labels = (const int*)d_in[3];
  float*       out    = (float*)d_out;

  char* ws = (char*)d_ws;
  // workspace layout (bytes)
  unsigned short* qn = (unsigned short*)(ws + 0);         // 1024*512*2   = 1,048,576
  unsigned short* kn = (unsigned short*)(ws + 1048576);   // 50304*512*2  = 51,511,296
  int*  perm = (int*)(ws + 52559872);                     // 50304*4 = 201,216
  int*  cls  = (int*)(ws + 52761088);                     // 50304*4 = 201,216
  int*  gz   = (int*)(ws + 52962304);                     // 6400*4: strided hist+cnt

  // 4 graph nodes: zero + prep2 + rank + main
  k_zero<<<7, 1024, 0, stream>>>(gz);
  k_prep2<<<(R4 + 3) / 4, 256, 0, stream>>>(keys, img, txt, labels, qn, kn, gz, out);
  k_rank<<<(KN_ROWS + 1023) / 1024, 1024, 0, stream>>>(labels, gz, gz + N_CLS * HS, perm, cls);
  k_main<<<dim3(8 * NT_TOT), 256, 0, stream>>>(qn, kn, cls, perm, out);
}